// Round 1
// 100.408 us; speedup vs baseline: 1.0060x; 1.0060x over previous
//
#include <hip/hip_runtime.h>
#include <math.h>

#define B_ 16
#define C_ 64
#define HW_ 4096          // 64*64
#define PHW_ 1024         // pooled 32*32

typedef __attribute__((ext_vector_type(8))) short bf8;    // 8 bf16 = 4 VGPR (MFMA A/B)
typedef __attribute__((ext_vector_type(16))) float fv16;  // 16 f32 (MFMA C/D 32x32)

union FU { bf8 v; unsigned u[4]; };

__device__ inline unsigned short f2bf(float f) {          // RNE f32->bf16
    unsigned u = __float_as_uint(f);
    return (unsigned short)((u + 0x7FFFu + ((u >> 16) & 1u)) >> 16);
}
__device__ inline unsigned packbf(float a, float b) {     // two f32 -> packed bf16x2 (RNE)
    return (unsigned)f2bf(a) | ((unsigned)f2bf(b) << 16);
}
__device__ inline unsigned packtr(float a, float b) {     // truncating pack (fast path)
    return (__float_as_uint(a) >> 16) | (__float_as_uint(b) & 0xFFFF0000u);
}
// v_permlane32_swap_b32: a.hi <-> b.lo.  After the call:
//   a = { a.lo (lanes 0-31) , b.lo-from-lanes-0-31 (lanes 32-63) }
//   b = { a.hi-from-lanes-32-63 (lanes 0-31) , b.hi (lanes 32-63) }
// This is exactly the {hi ? qk[j+2] : pk[j]} / {hi ? pk[j+2] : qk[j]} pair the
// old code built from 2x shfl_xor(32) + 2x cndmask.  One VALU op replaces
// 2 ds_bpermute + 2 v_cndmask (T12).
__device__ inline void pl32(unsigned &a, unsigned &b) {
    auto r = __builtin_amdgcn_permlane32_swap((int)a, (int)b, false, false);
    a = (unsigned)r[0]; b = (unsigned)r[1];
}

// ---------------------------------------------------------------------------
// Kernel 1: MFMA conv.  Changes vs R8 baseline:
//  * theta is now stored as bf16 packed [B][HW][8], pre-scaled by LOG2E
//    (bit-identical math: same f32 mul -> RNE pack order as the old attn
//    prologue).  One contiguous dwordx2 store per lane instead of 4 scattered
//    dword stores at 16 KB stride; halves theta bytes (2 MB -> 1 MB).
//  * phi_pack drops its zero half (was 2x inflated): [B][32][32][8].
// ---------------------------------------------------------------------------
__global__ __launch_bounds__(256) void conv_stage(
    const float* __restrict__ x,
    const float* __restrict__ Wt,   // [8][64]
    const float* __restrict__ Wp,   // [8][64]
    const float* __restrict__ Wg,   // [32][64]
    unsigned short* __restrict__ theta_pack,   // [B][HW][8] bf16, *LOG2E
    unsigned short* __restrict__ phi_pack,     // [B][32][32][8] bf16
    unsigned short* __restrict__ g_pack)       // [B][64][64][8] bf16
{
    __shared__ float sx[64][128];        // 32 KB, [c][px]
    __shared__ float poolh[2][40][33];   // per-image-row hmax, 10.3 KB

    const int t  = threadIdx.x;
    const int b  = blockIdx.x >> 5;
    const int h2 = blockIdx.x & 31;      // pooled row (image rows 2h2, 2h2+1)

    const float* xbase = x + (size_t)b * C_ * HW_ + h2 * 128;
    for (int f = t; f < 2048; f += 256) {
        int c = f >> 5, j4 = f & 31;
        *(float4*)&sx[c][j4 * 4] = *(const float4*)&xbase[(size_t)c * HW_ + j4 * 4];
    }

    const int wv = t >> 6, lane = t & 63, lo = lane & 31, hi = lane >> 5;

    FU wa[2][4];
    {
        const float* r0 = (lo < 8)  ? (Wt + lo * 64)
                        : (lo < 16) ? (Wp + (lo - 8) * 64)
                                    : (Wg + (lo - 16) * 64);
        const float* r1 = Wg + ((lo < 16) ? (16 + lo) : 0) * 64;
#pragma unroll
        for (int cs = 0; cs < 4; cs++) {
            const int c0 = cs * 16 + hi * 8;
            float4 a0 = *(const float4*)&r0[c0];
            float4 b0 = *(const float4*)&r0[c0 + 4];
            wa[0][cs].u[0] = packbf(a0.x, a0.y); wa[0][cs].u[1] = packbf(a0.z, a0.w);
            wa[0][cs].u[2] = packbf(b0.x, b0.y); wa[0][cs].u[3] = packbf(b0.z, b0.w);
            float4 a1 = *(const float4*)&r1[c0];
            float4 b1 = *(const float4*)&r1[c0 + 4];
            if (lo >= 16) { a1 = make_float4(0.f,0.f,0.f,0.f); b1 = make_float4(0.f,0.f,0.f,0.f); }
            wa[1][cs].u[0] = packbf(a1.x, a1.y); wa[1][cs].u[1] = packbf(a1.z, a1.w);
            wa[1][cs].u[2] = packbf(b1.x, b1.y); wa[1][cs].u[3] = packbf(b1.z, b1.w);
        }
    }
    __syncthreads();

    fv16 acc0, acc1;
#pragma unroll
    for (int r = 0; r < 16; r++) { acc0[r] = 0.f; acc1[r] = 0.f; }

    const int px = wv * 32 + lo;         // local pixel 0..127
#pragma unroll
    for (int cs = 0; cs < 4; cs++) {
        const float* sp = &sx[cs * 16 + hi * 8][px];
        float v[8];
#pragma unroll
        for (int j = 0; j < 8; j++) v[j] = sp[j * 128];
        FU xb;
        xb.u[0] = packbf(v[0], v[1]); xb.u[1] = packbf(v[2], v[3]);
        xb.u[2] = packbf(v[4], v[5]); xb.u[3] = packbf(v[6], v[7]);
        acc0 = __builtin_amdgcn_mfma_f32_32x32x16_bf16(wa[0][cs].v, xb.v, acc0, 0, 0, 0);
        acc1 = __builtin_amdgcn_mfma_f32_32x32x16_bf16(wa[1][cs].v, xb.v, acc1, 0, 0, 0);
    }

    {   // theta channels r+4*hi (r=0..3) for pixel px -> packed bf16 [pix][8]
        const float LOG2E = 1.4426950408889634f;
        unsigned u0 = packbf(acc0[0] * LOG2E, acc0[1] * LOG2E);
        unsigned u1 = packbf(acc0[2] * LOG2E, acc0[3] * LOG2E);
        unsigned short* tp = theta_pack + ((size_t)b * HW_ + h2 * 128 + px) * 8 + hi * 4;
        *(uint2*)tp = make_uint2(u0, u1);
    }

    const int prow = wv >> 1;
    const int pcol = (wv & 1) * 16 + (lo >> 1);
#pragma unroll
    for (int r = 4; r < 16; r++) {              // tile0: ch 8..31 -> pch 0..23
        float vv = acc0[r];
        float hm = fmaxf(vv, __shfl_xor(vv, 1));
        if ((lane & 1) == 0) {
            int m = (r & 3) + 8 * (r >> 2) + 4 * hi;   // 8..31
            poolh[prow][m - 8][pcol] = hm;
        }
    }
#pragma unroll
    for (int r = 0; r < 8; r++) {               // tile1: ch 32..47 -> pch 24..39
        float vv = acc1[r];
        float hm = fmaxf(vv, __shfl_xor(vv, 1));
        if ((lane & 1) == 0) {
            int m1 = (r & 3) + 8 * (r >> 2) + 4 * hi;  // 0..15
            poolh[prow][24 + m1][pcol] = hm;
        }
    }
    __syncthreads();

    if (t < 64) {
        if (t < 32) {                           // phi: real half only (no zero pad)
            float v[8];
#pragma unroll
            for (int j = 0; j < 8; j++)
                v[j] = fmaxf(poolh[0][j][t], poolh[1][j][t]);
            uint4 pkt = make_uint4(packbf(v[0], v[1]), packbf(v[2], v[3]),
                                   packbf(v[4], v[5]), packbf(v[6], v[7]));
            *(uint4*)(phi_pack + ((size_t)((b * 32 + h2) * 32 + t)) * 8) = pkt;
        }
    } else if (t < 192) {
        const int tt  = t - 64;
        const int ktl = tt >> 6;
        const int ln  = tt & 63;
        const int c   = ln & 31;
        const int hh  = ln >> 5;
        float v[8];
#pragma unroll
        for (int j = 0; j < 8; j++) {
            int p = ktl * 16 + hh * 8 + j;
            v[j] = fmaxf(poolh[0][8 + c][p], poolh[1][8 + c][p]);
        }
        uint4 pkt = make_uint4(packbf(v[0], v[1]), packbf(v[2], v[3]),
                               packbf(v[4], v[5]), packbf(v[6], v[7]));
        *(uint4*)(g_pack + ((size_t)((b * 64 + h2 * 2 + ktl) * 64 + ln)) * 8) = pkt;
    }
}

// ---------------------------------------------------------------------------
// Kernel 2: MFMA flash attention.  Keeps the R5/R8 simple "#pragma unroll 2"
// K-loop (R11 lesson: do NOT hand-pipeline — scratch spill catastrophe).
// Changes:
//  * half-exchange for the PV B-frag and the output frag now uses
//    v_permlane32_swap_b32 (1 VALU op) instead of 2 ds_bpermute + 2 cndmask
//    per word: -16 DS ops / -16 selects per K-iter-pair, -8/-8 in epilogue.
//  * theta prologue: single 16B load of pre-scaled bf16 (was 8 strided f32
//    loads + 8 muls + 4 packs).
//  * phi load exec-masked to lanes hi==0 (zeros kept in registers) — halves
//    repeated phi L2 traffic.
// All data movement is bit-identical to the previous version.
// ---------------------------------------------------------------------------
__global__ __launch_bounds__(256, 4) void attn_mfma(
    const unsigned short* __restrict__ theta_pack,  // [B][HW][8] bf16 *LOG2E
    const unsigned short* __restrict__ phi_pack,    // [B][32][32][8]
    const unsigned short* __restrict__ g_pack,      // [B][64][64][8]
    const float* __restrict__ Wa,                   // [64][32]
    const float* __restrict__ x,
    const float* __restrict__ sigma,
    float* __restrict__ out)
{
    __shared__ float comb[4][64][17];

    const int t = threadIdx.x, wave = t >> 6, lane = t & 63;
    const int lo = lane & 31, hi = lane >> 5;
    const int qtile = blockIdx.x * 2 + (wave >> 1);
    const int khalf = wave & 1;
    const int b = qtile >> 7, qt = qtile & 127;
    const int qg = qt * 32 + lo;                    // this lane's query column

    FU tb; tb.u[0] = tb.u[1] = tb.u[2] = tb.u[3] = 0;
    if (hi == 0) {
        uint4 p = *(const uint4*)(theta_pack + ((size_t)b * HW_ + qg) * 8);
        tb.u[0] = p.x; tb.u[1] = p.y; tb.u[2] = p.z; tb.u[3] = p.w;
    }

    fv16 zf, acc;
#pragma unroll
    for (int r = 0; r < 16; r++) { zf[r] = 0.f; acc[r] = 0.f; }
    float ps = 0.f;

    const int kt0 = khalf * 16;
    const unsigned short* phip = phi_pack + ((size_t)((b * 32 + kt0) * 32 + lo)) * 8;
    const unsigned short* gp   = g_pack   + ((size_t)((b * 64 + kt0 * 2) * 64 + lane)) * 8;

    FU pa; pa.u[0] = pa.u[1] = pa.u[2] = pa.u[3] = 0;   // hi==1 lanes stay zero

#pragma unroll 2
    for (int i = 0; i < 16; i++) {
        FU ga0, ga1;
        if (hi == 0) pa.v = *(const bf8*)(phip + (size_t)i * 256);
        ga0.v = *(const bf8*)(gp + (size_t)i * 1024);
        ga1.v = *(const bf8*)(gp + (size_t)i * 1024 + 512);
        fv16 s = __builtin_amdgcn_mfma_f32_32x32x16_bf16(pa.v, tb.v, zf, 0, 0, 0);

        {   // half A: C-regs 0..7 -> PV B-frag for ga0
            unsigned pk0, pk1, pk2, pk3;
            {
                float p0 = __builtin_amdgcn_exp2f(s[0]);
                float p1 = __builtin_amdgcn_exp2f(s[1]);
                ps += p0 + p1; pk0 = packtr(p0, p1);
            }
            {
                float p0 = __builtin_amdgcn_exp2f(s[2]);
                float p1 = __builtin_amdgcn_exp2f(s[3]);
                ps += p0 + p1; pk1 = packtr(p0, p1);
            }
            {
                float p0 = __builtin_amdgcn_exp2f(s[4]);
                float p1 = __builtin_amdgcn_exp2f(s[5]);
                ps += p0 + p1; pk2 = packtr(p0, p1);
            }
            {
                float p0 = __builtin_amdgcn_exp2f(s[6]);
                float p1 = __builtin_amdgcn_exp2f(s[7]);
                ps += p0 + p1; pk3 = packtr(p0, p1);
            }
            pl32(pk0, pk2); pl32(pk1, pk3);
            FU pb;
            pb.u[0] = pk0; pb.u[1] = pk1; pb.u[2] = pk2; pb.u[3] = pk3;
            acc = __builtin_amdgcn_mfma_f32_32x32x16_bf16(ga0.v, pb.v, acc, 0, 0, 0);
        }
        {   // half B: C-regs 8..15 -> PV B-frag for ga1
            unsigned pk0, pk1, pk2, pk3;
            {
                float p0 = __builtin_amdgcn_exp2f(s[8]);
                float p1 = __builtin_amdgcn_exp2f(s[9]);
                ps += p0 + p1; pk0 = packtr(p0, p1);
            }
            {
                float p0 = __builtin_amdgcn_exp2f(s[10]);
                float p1 = __builtin_amdgcn_exp2f(s[11]);
                ps += p0 + p1; pk1 = packtr(p0, p1);
            }
            {
                float p0 = __builtin_amdgcn_exp2f(s[12]);
                float p1 = __builtin_amdgcn_exp2f(s[13]);
                ps += p0 + p1; pk2 = packtr(p0, p1);
            }
            {
                float p0 = __builtin_amdgcn_exp2f(s[14]);
                float p1 = __builtin_amdgcn_exp2f(s[15]);
                ps += p0 + p1; pk3 = packtr(p0, p1);
            }
            pl32(pk0, pk2); pl32(pk1, pk3);
            FU pb;
            pb.u[0] = pk0; pb.u[1] = pk1; pb.u[2] = pk2; pb.u[3] = pk3;
            acc = __builtin_amdgcn_mfma_f32_32x32x16_bf16(ga1.v, pb.v, acc, 0, 0, 0);
        }
    }

#pragma unroll
    for (int r = 0; r < 16; r++) comb[wave][lane][r] = acc[r];
    comb[wave][lane][16] = ps;
    __syncthreads();
    const int pw = wave ^ 1;
#pragma unroll
    for (int r = 0; r < 16; r++) acc[r] += comb[pw][lane][r];
    ps += comb[pw][lane][16];

    float lsum = ps + __shfl_xor(ps, 32);
    float inv = 1.f / lsum;

    float on[16];
#pragma unroll
    for (int r = 0; r < 16; r++) on[r] = acc[r] * inv;
    unsigned pk[8];
#pragma unroll
    for (int i = 0; i < 8; i++) pk[i] = packtr(on[2 * i], on[2 * i + 1]);
    pl32(pk[0], pk[2]); pl32(pk[1], pk[3]);
    pl32(pk[4], pk[6]); pl32(pk[5], pk[7]);
    FU ob0, ob1;
    ob0.u[0] = pk[0]; ob0.u[1] = pk[1]; ob0.u[2] = pk[2]; ob0.u[3] = pk[3];
    ob1.u[0] = pk[4]; ob1.u[1] = pk[5]; ob1.u[2] = pk[6]; ob1.u[3] = pk[7];

    FU wa0, wa1;
    {
        const float* wr = Wa + (khalf * 32 + lo) * 32;
#pragma unroll
        for (int ktw = 0; ktw < 2; ktw++) {
            float w8[8];
#pragma unroll
            for (int j = 0; j < 8; j++) w8[j] = wr[ktw * 16 + hi * 8 + j];
            FU f;
            f.u[0] = packbf(w8[0], w8[1]); f.u[1] = packbf(w8[2], w8[3]);
            f.u[2] = packbf(w8[4], w8[5]); f.u[3] = packbf(w8[6], w8[7]);
            if (ktw == 0) wa0 = f; else wa1 = f;
        }
    }
    fv16 d2 = __builtin_amdgcn_mfma_f32_32x32x16_bf16(wa0.v, ob0.v, zf, 0, 0, 0);
    d2 = __builtin_amdgcn_mfma_f32_32x32x16_bf16(wa1.v, ob1.v, d2, 0, 0, 0);

    const float sig = sigma[0];
#pragma unroll
    for (int r = 0; r < 16; r++) {
        int row = (r & 3) + ((r >> 2) << 3) + (hi << 2);
        int o = khalf * 32 + row;
        size_t idx = (((size_t)b * 64 + o) << 12) + qg;
        out[idx] = x[idx] + sig * d2[r];
    }
}

// ---------------------------------------------------------------------------
extern "C" void kernel_launch(void* const* d_in, const int* in_sizes, int n_in,
                              void* d_out, int out_size, void* d_ws, size_t ws_size,
                              hipStream_t stream) {
    const float* x     = (const float*)d_in[0];
    const float* Wt    = (const float*)d_in[1];
    const float* Wp    = (const float*)d_in[2];
    const float* Wg    = (const float*)d_in[3];
    const float* Wa    = (const float*)d_in[4];
    const float* sigma = (const float*)d_in[5];
    float* out = (float*)d_out;

    // ws layout: theta_pack bf16 (1 MB) | phi_pack bf16 (256 KB) | g_pack bf16 (1 MB)
    unsigned short* theta_pack = (unsigned short*)d_ws;                  // B*HW*8
    unsigned short* phi_pack   = theta_pack + (size_t)B_ * HW_ * 8;      // B*32*32*8
    unsigned short* g_pack     = phi_pack + (size_t)B_ * 32 * 32 * 8;    // B*64*64*8

    conv_stage<<<512, 256, 0, stream>>>(x, Wt, Wp, Wg, theta_pack, phi_pack, g_pack);
    attn_mfma<<<1024, 256, 0, stream>>>(theta_pack, phi_pack, g_pack, Wa, x, sigma, out);
}

// Round 2
// 98.464 us; speedup vs baseline: 1.0259x; 1.0197x over previous
//
#include <hip/hip_runtime.h>
#include <math.h>

#define B_ 16
#define C_ 64
#define HW_ 4096          // 64*64
#define PHW_ 1024         // pooled 32*32

typedef __attribute__((ext_vector_type(8))) short bf8;    // 8 bf16 = 4 VGPR (MFMA A/B)
typedef __attribute__((ext_vector_type(16))) float fv16;  // 16 f32 (MFMA C/D 32x32)

union FU { bf8 v; unsigned u[4]; };

__device__ inline unsigned short f2bf(float f) {          // RNE f32->bf16
    unsigned u = __float_as_uint(f);
    return (unsigned short)((u + 0x7FFFu + ((u >> 16) & 1u)) >> 16);
}
__device__ inline unsigned packbf(float a, float b) {     // two f32 -> packed bf16x2 (RNE)
    return (unsigned)f2bf(a) | ((unsigned)f2bf(b) << 16);
}
// truncating pack as ONE v_perm_b32: D = {lo16 = a[31:16], hi16 = b[31:16]}.
// sel bytes (LSB->MSB): 0x02(a.b2), 0x03(a.b3), 0x06(b.b2), 0x07(b.b3);
// v_perm_b32 sel values 0-3 pick S1 (=a), 4-7 pick S0 (=b).
// Bit-identical to (a>>16)|(b&0xFFFF0000), 1 VALU op instead of 3.
__device__ inline unsigned packtr(float a, float b) {
    return __builtin_amdgcn_perm(__float_as_uint(b), __float_as_uint(a), 0x07060302u);
}
// v_permlane32_swap_b32: a.hi <-> b.lo (T12) — one VALU op replaces
// 2 ds_bpermute + 2 v_cndmask for the lane<32/lane>=32 half exchange.
__device__ inline void pl32(unsigned &a, unsigned &b) {
    auto r = __builtin_amdgcn_permlane32_swap((int)a, (int)b, false, false);
    a = (unsigned)r[0]; b = (unsigned)r[1];
}

// ---------------------------------------------------------------------------
// Kernel 1: MFMA conv (unchanged from R1 — theta bf16 [B][HW][8] *LOG2E,
// phi_pack real-half-only [B][32][32][8]).
// ---------------------------------------------------------------------------
__global__ __launch_bounds__(256) void conv_stage(
    const float* __restrict__ x,
    const float* __restrict__ Wt,   // [8][64]
    const float* __restrict__ Wp,   // [8][64]
    const float* __restrict__ Wg,   // [32][64]
    unsigned short* __restrict__ theta_pack,   // [B][HW][8] bf16, *LOG2E
    unsigned short* __restrict__ phi_pack,     // [B][32][32][8] bf16
    unsigned short* __restrict__ g_pack)       // [B][64][64][8] bf16
{
    __shared__ float sx[64][128];        // 32 KB, [c][px]
    __shared__ float poolh[2][40][33];   // per-image-row hmax, 10.3 KB

    const int t  = threadIdx.x;
    const int b  = blockIdx.x >> 5;
    const int h2 = blockIdx.x & 31;      // pooled row (image rows 2h2, 2h2+1)

    const float* xbase = x + (size_t)b * C_ * HW_ + h2 * 128;
    for (int f = t; f < 2048; f += 256) {
        int c = f >> 5, j4 = f & 31;
        *(float4*)&sx[c][j4 * 4] = *(const float4*)&xbase[(size_t)c * HW_ + j4 * 4];
    }

    const int wv = t >> 6, lane = t & 63, lo = lane & 31, hi = lane >> 5;

    FU wa[2][4];
    {
        const float* r0 = (lo < 8)  ? (Wt + lo * 64)
                        : (lo < 16) ? (Wp + (lo - 8) * 64)
                                    : (Wg + (lo - 16) * 64);
        const float* r1 = Wg + ((lo < 16) ? (16 + lo) : 0) * 64;
#pragma unroll
        for (int cs = 0; cs < 4; cs++) {
            const int c0 = cs * 16 + hi * 8;
            float4 a0 = *(const float4*)&r0[c0];
            float4 b0 = *(const float4*)&r0[c0 + 4];
            wa[0][cs].u[0] = packbf(a0.x, a0.y); wa[0][cs].u[1] = packbf(a0.z, a0.w);
            wa[0][cs].u[2] = packbf(b0.x, b0.y); wa[0][cs].u[3] = packbf(b0.z, b0.w);
            float4 a1 = *(const float4*)&r1[c0];
            float4 b1 = *(const float4*)&r1[c0 + 4];
            if (lo >= 16) { a1 = make_float4(0.f,0.f,0.f,0.f); b1 = make_float4(0.f,0.f,0.f,0.f); }
            wa[1][cs].u[0] = packbf(a1.x, a1.y); wa[1][cs].u[1] = packbf(a1.z, a1.w);
            wa[1][cs].u[2] = packbf(b1.x, b1.y); wa[1][cs].u[3] = packbf(b1.z, b1.w);
        }
    }
    __syncthreads();

    fv16 acc0, acc1;
#pragma unroll
    for (int r = 0; r < 16; r++) { acc0[r] = 0.f; acc1[r] = 0.f; }

    const int px = wv * 32 + lo;         // local pixel 0..127
#pragma unroll
    for (int cs = 0; cs < 4; cs++) {
        const float* sp = &sx[cs * 16 + hi * 8][px];
        float v[8];
#pragma unroll
        for (int j = 0; j < 8; j++) v[j] = sp[j * 128];
        FU xb;
        xb.u[0] = packbf(v[0], v[1]); xb.u[1] = packbf(v[2], v[3]);
        xb.u[2] = packbf(v[4], v[5]); xb.u[3] = packbf(v[6], v[7]);
        acc0 = __builtin_amdgcn_mfma_f32_32x32x16_bf16(wa[0][cs].v, xb.v, acc0, 0, 0, 0);
        acc1 = __builtin_amdgcn_mfma_f32_32x32x16_bf16(wa[1][cs].v, xb.v, acc1, 0, 0, 0);
    }

    {   // theta channels r+4*hi (r=0..3) for pixel px -> packed bf16 [pix][8]
        const float LOG2E = 1.4426950408889634f;
        unsigned u0 = packbf(acc0[0] * LOG2E, acc0[1] * LOG2E);
        unsigned u1 = packbf(acc0[2] * LOG2E, acc0[3] * LOG2E);
        unsigned short* tp = theta_pack + ((size_t)b * HW_ + h2 * 128 + px) * 8 + hi * 4;
        *(uint2*)tp = make_uint2(u0, u1);
    }

    const int prow = wv >> 1;
    const int pcol = (wv & 1) * 16 + (lo >> 1);
#pragma unroll
    for (int r = 4; r < 16; r++) {              // tile0: ch 8..31 -> pch 0..23
        float vv = acc0[r];
        float hm = fmaxf(vv, __shfl_xor(vv, 1));
        if ((lane & 1) == 0) {
            int m = (r & 3) + 8 * (r >> 2) + 4 * hi;   // 8..31
            poolh[prow][m - 8][pcol] = hm;
        }
    }
#pragma unroll
    for (int r = 0; r < 8; r++) {               // tile1: ch 32..47 -> pch 24..39
        float vv = acc1[r];
        float hm = fmaxf(vv, __shfl_xor(vv, 1));
        if ((lane & 1) == 0) {
            int m1 = (r & 3) + 8 * (r >> 2) + 4 * hi;  // 0..15
            poolh[prow][24 + m1][pcol] = hm;
        }
    }
    __syncthreads();

    if (t < 64) {
        if (t < 32) {                           // phi: real half only (no zero pad)
            float v[8];
#pragma unroll
            for (int j = 0; j < 8; j++)
                v[j] = fmaxf(poolh[0][j][t], poolh[1][j][t]);
            uint4 pkt = make_uint4(packbf(v[0], v[1]), packbf(v[2], v[3]),
                                   packbf(v[4], v[5]), packbf(v[6], v[7]));
            *(uint4*)(phi_pack + ((size_t)((b * 32 + h2) * 32 + t)) * 8) = pkt;
        }
    } else if (t < 192) {
        const int tt  = t - 64;
        const int ktl = tt >> 6;
        const int ln  = tt & 63;
        const int c   = ln & 31;
        const int hh  = ln >> 5;
        float v[8];
#pragma unroll
        for (int j = 0; j < 8; j++) {
            int p = ktl * 16 + hh * 8 + j;
            v[j] = fmaxf(poolh[0][8 + c][p], poolh[1][8 + c][p]);
        }
        uint4 pkt = make_uint4(packbf(v[0], v[1]), packbf(v[2], v[3]),
                               packbf(v[4], v[5]), packbf(v[6], v[7]));
        *(uint4*)(g_pack + ((size_t)((b * 64 + h2 * 2 + ktl) * 64 + ln)) * 8) = pkt;
    }
}

// ---------------------------------------------------------------------------
// Kernel 2: MFMA flash attention.
// R2 change: one-deep REGISTER PREFETCH of pa/ga0/ga1 (T14 light form).
// Theory: R1's permlane win was null because the loop is stall-bound, not
// issue-bound — pa is loaded and consumed by the QK MFMA in the same
// iteration, exposing ~200 cy of L2 latency per iter.  Prefetch issues
// iteration i+1's three loads (wrap-indexed, branchless) before iteration
// i's compute, hiding the latency under the ~230-cy exp/pack/MFMA phase.
// Named cur/next registers only (+12 VGPR) — NOT R11's full-unroll rotation
// (scratch-spill catastrophe).  packtr is now a single v_perm_b32.
// All data movement and FP order bit-identical to R1.
// ---------------------------------------------------------------------------
__global__ __launch_bounds__(256, 4) void attn_mfma(
    const unsigned short* __restrict__ theta_pack,  // [B][HW][8] bf16 *LOG2E
    const unsigned short* __restrict__ phi_pack,    // [B][32][32][8]
    const unsigned short* __restrict__ g_pack,      // [B][64][64][8]
    const float* __restrict__ Wa,                   // [64][32]
    const float* __restrict__ x,
    const float* __restrict__ sigma,
    float* __restrict__ out)
{
    __shared__ float comb[4][64][17];

    const int t = threadIdx.x, wave = t >> 6, lane = t & 63;
    const int lo = lane & 31, hi = lane >> 5;
    const int qtile = blockIdx.x * 2 + (wave >> 1);
    const int khalf = wave & 1;
    const int b = qtile >> 7, qt = qtile & 127;
    const int qg = qt * 32 + lo;                    // this lane's query column

    FU tb; tb.u[0] = tb.u[1] = tb.u[2] = tb.u[3] = 0;
    if (hi == 0) {
        uint4 p = *(const uint4*)(theta_pack + ((size_t)b * HW_ + qg) * 8);
        tb.u[0] = p.x; tb.u[1] = p.y; tb.u[2] = p.z; tb.u[3] = p.w;
    }

    fv16 zf, acc;
#pragma unroll
    for (int r = 0; r < 16; r++) { zf[r] = 0.f; acc[r] = 0.f; }
    float ps = 0.f;

    const int kt0 = khalf * 16;
    const unsigned short* phip = phi_pack + ((size_t)((b * 32 + kt0) * 32 + lo)) * 8;
    const unsigned short* gp   = g_pack   + ((size_t)((b * 64 + kt0 * 2) * 64 + lane)) * 8;

    // --- prologue: load iteration 0 into the "current" registers ---------
    FU paC, g0C, g1C;
    paC.u[0] = paC.u[1] = paC.u[2] = paC.u[3] = 0;      // hi==1 lanes stay zero
    if (hi == 0) paC.v = *(const bf8*)(phip);
    g0C.v = *(const bf8*)(gp);
    g1C.v = *(const bf8*)(gp + 512);

#pragma unroll 2
    for (int i = 0; i < 16; i++) {
        // --- issue next iteration's loads FIRST (wrap at 15 -> reload 0,
        //     branchless; data is L2-hot so the extra load is free) -------
        const int ip = (i + 1) & 15;
        FU paN, g0N, g1N;
        paN.u[0] = paN.u[1] = paN.u[2] = paN.u[3] = 0;
        if (hi == 0) paN.v = *(const bf8*)(phip + (size_t)ip * 256);
        g0N.v = *(const bf8*)(gp + (size_t)ip * 1024);
        g1N.v = *(const bf8*)(gp + (size_t)ip * 1024 + 512);

        // --- compute iteration i from the current registers --------------
        fv16 s = __builtin_amdgcn_mfma_f32_32x32x16_bf16(paC.v, tb.v, zf, 0, 0, 0);

        {   // half A: C-regs 0..7 -> PV B-frag for g0C
            unsigned pk0, pk1, pk2, pk3;
            {
                float p0 = __builtin_amdgcn_exp2f(s[0]);
                float p1 = __builtin_amdgcn_exp2f(s[1]);
                ps += p0 + p1; pk0 = packtr(p0, p1);
            }
            {
                float p0 = __builtin_amdgcn_exp2f(s[2]);
                float p1 = __builtin_amdgcn_exp2f(s[3]);
                ps += p0 + p1; pk1 = packtr(p0, p1);
            }
            {
                float p0 = __builtin_amdgcn_exp2f(s[4]);
                float p1 = __builtin_amdgcn_exp2f(s[5]);
                ps += p0 + p1; pk2 = packtr(p0, p1);
            }
            {
                float p0 = __builtin_amdgcn_exp2f(s[6]);
                float p1 = __builtin_amdgcn_exp2f(s[7]);
                ps += p0 + p1; pk3 = packtr(p0, p1);
            }
            pl32(pk0, pk2); pl32(pk1, pk3);
            FU pb;
            pb.u[0] = pk0; pb.u[1] = pk1; pb.u[2] = pk2; pb.u[3] = pk3;
            acc = __builtin_amdgcn_mfma_f32_32x32x16_bf16(g0C.v, pb.v, acc, 0, 0, 0);
        }
        {   // half B: C-regs 8..15 -> PV B-frag for g1C
            unsigned pk0, pk1, pk2, pk3;
            {
                float p0 = __builtin_amdgcn_exp2f(s[8]);
                float p1 = __builtin_amdgcn_exp2f(s[9]);
                ps += p0 + p1; pk0 = packtr(p0, p1);
            }
            {
                float p0 = __builtin_amdgcn_exp2f(s[10]);
                float p1 = __builtin_amdgcn_exp2f(s[11]);
                ps += p0 + p1; pk1 = packtr(p0, p1);
            }
            {
                float p0 = __builtin_amdgcn_exp2f(s[12]);
                float p1 = __builtin_amdgcn_exp2f(s[13]);
                ps += p0 + p1; pk2 = packtr(p0, p1);
            }
            {
                float p0 = __builtin_amdgcn_exp2f(s[14]);
                float p1 = __builtin_amdgcn_exp2f(s[15]);
                ps += p0 + p1; pk3 = packtr(p0, p1);
            }
            pl32(pk0, pk2); pl32(pk1, pk3);
            FU pb;
            pb.u[0] = pk0; pb.u[1] = pk1; pb.u[2] = pk2; pb.u[3] = pk3;
            acc = __builtin_amdgcn_mfma_f32_32x32x16_bf16(g1C.v, pb.v, acc, 0, 0, 0);
        }

        // --- rotate: next becomes current (pure register renaming) -------
        paC = paN; g0C = g0N; g1C = g1N;
    }

#pragma unroll
    for (int r = 0; r < 16; r++) comb[wave][lane][r] = acc[r];
    comb[wave][lane][16] = ps;
    __syncthreads();
    const int pw = wave ^ 1;
#pragma unroll
    for (int r = 0; r < 16; r++) acc[r] += comb[pw][lane][r];
    ps += comb[pw][lane][16];

    float lsum = ps + __shfl_xor(ps, 32);
    float inv = 1.f / lsum;

    float on[16];
#pragma unroll
    for (int r = 0; r < 16; r++) on[r] = acc[r] * inv;
    unsigned pk[8];
#pragma unroll
    for (int i = 0; i < 8; i++) pk[i] = packtr(on[2 * i], on[2 * i + 1]);
    pl32(pk[0], pk[2]); pl32(pk[1], pk[3]);
    pl32(pk[4], pk[6]); pl32(pk[5], pk[7]);
    FU ob0, ob1;
    ob0.u[0] = pk[0]; ob0.u[1] = pk[1]; ob0.u[2] = pk[2]; ob0.u[3] = pk[3];
    ob1.u[0] = pk[4]; ob1.u[1] = pk[5]; ob1.u[2] = pk[6]; ob1.u[3] = pk[7];

    FU wa0, wa1;
    {
        const float* wr = Wa + (khalf * 32 + lo) * 32;
#pragma unroll
        for (int ktw = 0; ktw < 2; ktw++) {
            float w8[8];
#pragma unroll
            for (int j = 0; j < 8; j++) w8[j] = wr[ktw * 16 + hi * 8 + j];
            FU f;
            f.u[0] = packbf(w8[0], w8[1]); f.u[1] = packbf(w8[2], w8[3]);
            f.u[2] = packbf(w8[4], w8[5]); f.u[3] = packbf(w8[6], w8[7]);
            if (ktw == 0) wa0 = f; else wa1 = f;
        }
    }
    fv16 d2 = __builtin_amdgcn_mfma_f32_32x32x16_bf16(wa0.v, ob0.v, zf, 0, 0, 0);
    d2 = __builtin_amdgcn_mfma_f32_32x32x16_bf16(wa1.v, ob1.v, d2, 0, 0, 0);

    const float sig = sigma[0];
#pragma unroll
    for (int r = 0; r < 16; r++) {
        int row = (r & 3) + ((r >> 2) << 3) + (hi << 2);
        int o = khalf * 32 + row;
        size_t idx = (((size_t)b * 64 + o) << 12) + qg;
        out[idx] = x[idx] + sig * d2[r];
    }
}

// ---------------------------------------------------------------------------
extern "C" void kernel_launch(void* const* d_in, const int* in_sizes, int n_in,
                              void* d_out, int out_size, void* d_ws, size_t ws_size,
                              hipStream_t stream) {
    const float* x     = (const float*)d_in[0];
    const float* Wt    = (const float*)d_in[1];
    const float* Wp    = (const float*)d_in[2];
    const float* Wg    = (const float*)d_in[3];
    const float* Wa    = (const float*)d_in[4];
    const float* sigma = (const float*)d_in[5];
    float* out = (float*)d_out;

    // ws layout: theta_pack bf16 (1 MB) | phi_pack bf16 (256 KB) | g_pack bf16 (1 MB)
    unsigned short* theta_pack = (unsigned short*)d_ws;                  // B*HW*8
    unsigned short* phi_pack   = theta_pack + (size_t)B_ * HW_ * 8;      // B*32*32*8
    unsigned short* g_pack     = phi_pack + (size_t)B_ * 32 * 32 * 8;    // B*64*64*8

    conv_stage<<<512, 256, 0, stream>>>(x, Wt, Wp, Wg, theta_pack, phi_pack, g_pack);
    attn_mfma<<<1024, 256, 0, stream>>>(theta_pack, phi_pack, g_pack, Wa, x, sigma, out);
}